// Round 2
// baseline (261.575 us; speedup 1.0000x reference)
//
#include <hip/hip_runtime.h>
#include <math.h>

#define N_PTS 2048
#define M_PTS 128
#define INNF  256
#define H     128

#define MIN_STDC 0.30235680f   /* 0.32*1.88973/2 */
#define MAX_STDC 2.19208680f   /* 2.32*1.88973/2 */
#define PI_F     3.14159265358979f
#define LOG2E_F  1.44269504089f

static __device__ __forceinline__ float silu_f(float x) {
  return x / (1.0f + __expf(-x));
}

// ---------------------------------------------------------------------------
// K0: spherical harmonics + d^2 for all (n,m) pairs.
// SH layout [n][m][12]: {1, x, y, z, s3xz, s3xy, yy-0.5(xx+zz), s3yz,
//                        0.5*s3*(zz-xx), d2, 0, 0}
// ---------------------------------------------------------------------------
__global__ __launch_bounds__(256) void k_sh(const float* __restrict__ gc,
                                            const float* __restrict__ cc,
                                            float* __restrict__ SH) {
  int p = blockIdx.x * 256 + threadIdx.x;     // 0 .. N*M-1
  int n = p >> 7, m = p & 127;
  float gx = gc[3*n], gy = gc[3*n+1], gz = gc[3*n+2];
  float cx = cc[3*m], cy = cc[3*m+1], cz = cc[3*m+2];
  float dx = gx - cx, dy = gy - cy, dz = gz - cz;
  float d2 = dx*dx + dy*dy + dz*dz + 3e-20f;
  float inv = rsqrtf(d2);
  float x = dx*inv, y = dy*inv, z = dz*inv;
  const float s3 = 1.73205080757f;
  float4 q0 = make_float4(1.0f, x, y, z);
  float4 q1 = make_float4(s3*x*z, s3*x*y, y*y - 0.5f*(x*x + z*z), s3*y*z);
  float4 q2 = make_float4(0.5f*s3*(z*z - x*x), d2, 0.0f, 0.0f);
  float4* dst = (float4*)(SH + (size_t)p * 12);
  dst[0] = q0; dst[1] = q1; dst[2] = q2;
}

// ---------------------------------------------------------------------------
// K1: hpre = silu(h @ W_pre + b_pre)  (kept in LDS), then
//     hdg[l][n][w] = (hpre @ W_down[l])[n,w] * gw[n] * coef(w) / sqrt(2l+1)
// ---------------------------------------------------------------------------
__global__ __launch_bounds__(128) void k_pre(const float* __restrict__ h,
    const float* __restrict__ W_pre, const float* __restrict__ b_pre,
    const float* __restrict__ W_down, const float* __restrict__ gw,
    float* __restrict__ hdg) {
  __shared__ float h_t[INNF * 10];   // [u][n]
  __shared__ float hp_t[H * 10];
  int t = threadIdx.x;
  int n0 = blockIdx.x * 8;
  int tgn = t >> 5;          // 0..3 -> n = 2*tgn + r
  int tgw = t & 31;          // w = 4*tgw + c

  #pragma unroll
  for (int i = 0; i < 4; ++i) {
    int j = t + i * 128;
    int n = j >> 6, uq = (j & 63) << 2;
    float4 v = *(const float4*)(h + (size_t)(n0 + n) * INNF + uq);
    h_t[(uq+0)*10 + n] = v.x;
    h_t[(uq+1)*10 + n] = v.y;
    h_t[(uq+2)*10 + n] = v.z;
    h_t[(uq+3)*10 + n] = v.w;
  }
  __syncthreads();

  float acc[2][4] = {};
  #pragma unroll 4
  for (int u = 0; u < INNF; ++u) {
    float2 a = *(const float2*)&h_t[u*10 + 2*tgn];
    float4 wv = *(const float4*)(W_pre + u*H + 4*tgw);
    acc[0][0] += a.x*wv.x; acc[0][1] += a.x*wv.y; acc[0][2] += a.x*wv.z; acc[0][3] += a.x*wv.w;
    acc[1][0] += a.y*wv.x; acc[1][1] += a.y*wv.y; acc[1][2] += a.y*wv.z; acc[1][3] += a.y*wv.w;
  }
  float4 bv = *(const float4*)(b_pre + 4*tgw);
  float bb[4] = {bv.x, bv.y, bv.z, bv.w};
  #pragma unroll
  for (int r = 0; r < 2; ++r)
    #pragma unroll
    for (int c = 0; c < 4; ++c) {
      float v = silu_f(acc[r][c] + bb[c]);
      hp_t[(4*tgw + c)*10 + 2*tgn + r] = v;
    }
  __syncthreads();

  float coef[4];
  const float stp = (MAX_STDC - MIN_STDC) / 127.0f;
  #pragma unroll
  for (int c = 0; c < 4; ++c) {
    int w = 4*tgw + c;
    float s = MIN_STDC + (float)w * stp;
    float temps = 2.0f * s * s;
    coef[c] = (2.0f/3.0f) / (temps * powf(PI_F * temps, 1.5f));
  }
  float gw2[2] = {gw[n0 + 2*tgn], gw[n0 + 2*tgn + 1]};

  for (int l = 0; l < 3; ++l) {
    float a2[2][4] = {};
    #pragma unroll 4
    for (int u = 0; u < H; ++u) {
      float2 a = *(const float2*)&hp_t[u*10 + 2*tgn];
      float4 wv = *(const float4*)(W_down + (size_t)(l*H + u)*H + 4*tgw);
      a2[0][0] += a.x*wv.x; a2[0][1] += a.x*wv.y; a2[0][2] += a.x*wv.z; a2[0][3] += a.x*wv.w;
      a2[1][0] += a.y*wv.x; a2[1][1] += a.y*wv.y; a2[1][2] += a.y*wv.z; a2[1][3] += a.y*wv.w;
    }
    float invn = (l == 0) ? 1.0f : (l == 1 ? 0.57735026919f : 0.44721359550f);
    #pragma unroll
    for (int r = 0; r < 2; ++r) {
      float sc = gw2[r] * invn;
      float4 o = make_float4(a2[r][0]*sc*coef[0], a2[r][1]*sc*coef[1],
                             a2[r][2]*sc*coef[2], a2[r][3]*sc*coef[3]);
      *(float4*)(hdg + ((size_t)l*N_PTS + n0 + 2*tgn + r)*H + 4*tgw) = o;
    }
  }
}

// ---------------------------------------------------------------------------
// K2: pair loop ("down"). Thread = w, block = 4 m's x 64 n's. 1024 blocks.
// Manual unroll-4 over n with hdg loads batched for ILP.
// ---------------------------------------------------------------------------
__global__ __launch_bounds__(128) void k_down(const float* __restrict__ SH,
    const float* __restrict__ hdg, float* __restrict__ c_part) {
  int t = threadIdx.x;
  int m0 = blockIdx.x * 4;
  int s  = blockIdx.y;        // 0..31
  int n0 = s * 64;
  const float stp = (MAX_STDC - MIN_STDC) / 127.0f;
  float sw = MIN_STDC + (float)t * stp;
  float nl2t = LOG2E_F / (2.0f * sw * sw);   // log2(e)/temps -> bare v_exp_f32
  float acc[4][9] = {};
  for (int nn = 0; nn < 64; nn += 4) {
    float a0[4], a1[4], a2[4];
    #pragma unroll
    for (int j = 0; j < 4; ++j) {
      size_t n = (size_t)(n0 + nn + j);
      a0[j] = hdg[n*H + t];
      a1[j] = hdg[((size_t)N_PTS + n)*H + t];
      a2[j] = hdg[((size_t)2*N_PTS + n)*H + t];
    }
    #pragma unroll
    for (int j = 0; j < 4; ++j) {
      const float* shb = SH + (((size_t)(n0 + nn + j))*M_PTS + m0) * 12;
      #pragma unroll
      for (int mm = 0; mm < 4; ++mm) {
        float4 q0 = *(const float4*)(shb + mm*12);
        float4 q1 = *(const float4*)(shb + mm*12 + 4);
        float4 q2 = *(const float4*)(shb + mm*12 + 8);
        float e  = exp2f(-q2.y * nl2t);
        float rp = e * q2.y;
        float t0 = a0[j]*rp, t1 = a1[j]*rp, t2 = a2[j]*rp;
        acc[mm][0] += t0;
        acc[mm][1] += t1*q0.y; acc[mm][2] += t1*q0.z; acc[mm][3] += t1*q0.w;
        acc[mm][4] += t2*q1.x; acc[mm][5] += t2*q1.y;
        acc[mm][6] += t2*q1.z; acc[mm][7] += t2*q1.w;
        acc[mm][8] += t2*q2.x;
      }
    }
  }
  #pragma unroll
  for (int mm = 0; mm < 4; ++mm)
    #pragma unroll
    for (int li = 0; li < 9; ++li)
      c_part[(((size_t)s*M_PTS + m0 + mm)*9 + li)*H + t] = acc[mm][li];
}

// ---------------------------------------------------------------------------
// K3: reduce partials over s (32), apply W_up + up-norm -> CU[m][12][w].
// Split by l so the 2l+1 loops are compile-time; grid (128, 3).
// ---------------------------------------------------------------------------
template<int L>
static __device__ __forceinline__ void cu_body(float* c_lds,
    const float* __restrict__ c_part, const float* __restrict__ W_up,
    float* __restrict__ CU, int m, int t) {
  constexpr int LI0 = L * L;
  constexpr int CNT = 2 * L + 1;
  #pragma unroll
  for (int k = 0; k < CNT; ++k) {
    float v = 0.0f;
    #pragma unroll
    for (int s = 0; s < 32; ++s)
      v += c_part[(((size_t)s*M_PTS + m)*9 + LI0 + k)*H + t];
    c_lds[k*H + t] = v;
  }
  __syncthreads();
  float acc[CNT] = {};
  #pragma unroll 4
  for (int u = 0; u < H; ++u) {
    float wv = W_up[((size_t)L*H + u)*H + t];
    #pragma unroll
    for (int k = 0; k < CNT; ++k)
      acc[k] += c_lds[k*H + u] * wv;
  }
  const float invn = (L == 0) ? 1.0f : (L == 1 ? 0.57735026919f : 0.44721359550f);
  #pragma unroll
  for (int k = 0; k < CNT; ++k)
    CU[((size_t)m*12 + LI0 + k)*H + t] = acc[k] * invn;
}

__global__ __launch_bounds__(128) void k_cu(const float* __restrict__ c_part,
    const float* __restrict__ W_up, float* __restrict__ CU) {
  __shared__ float c_lds[5 * H];
  int t = threadIdx.x, m = blockIdx.x, l = blockIdx.y;
  if (l == 0) {
    cu_body<0>(c_lds, c_part, W_up, CU, m, t);
    #pragma unroll
    for (int li = 9; li < 12; ++li)
      CU[((size_t)m*12 + li)*H + t] = 0.0f;
  } else if (l == 1) {
    cu_body<1>(c_lds, c_part, W_up, CU, m, t);
  } else {
    cu_body<2>(c_lds, c_part, W_up, CU, m, t);
  }
}

// ---------------------------------------------------------------------------
// K4: up GEMM  out_pre[2048 x 128] = SH[2048 x 1536] @ CU[1536 x 128],
// split-K over 8 chunks of 192. Block tile 64n x 128w, thread tile 4n x 8w.
// ---------------------------------------------------------------------------
__global__ __launch_bounds__(256) void k_up(const float* __restrict__ SH,
    const float* __restrict__ CU, float* __restrict__ out_part) {
  __shared__ float At[32 * 68];    // [k][n] padded
  __shared__ float Bl[32 * 128];   // [k][w]
  int t = threadIdx.x;
  int n0 = blockIdx.x * 64;
  int ks = blockIdx.y;
  int tgn = t >> 4, tgw = t & 15;
  float acc[4][8] = {};
  for (int ch = 0; ch < 6; ++ch) {
    int kc = ks*192 + ch*32;
    #pragma unroll
    for (int i = 0; i < 2; ++i) {           // stage A (transposed)
      int idx = t + i*256;
      int n = idx >> 3, q = (idx & 7) << 2;
      float4 v = *(const float4*)(SH + (size_t)(n0 + n)*1536 + kc + q);
      At[(q+0)*68 + n] = v.x; At[(q+1)*68 + n] = v.y;
      At[(q+2)*68 + n] = v.z; At[(q+3)*68 + n] = v.w;
    }
    #pragma unroll
    for (int i = 0; i < 4; ++i) {           // stage B
      int idx = t + i*256;
      int k = idx >> 5, q = (idx & 31) << 2;
      *(float4*)&Bl[k*128 + q] = *(const float4*)(CU + (size_t)(kc + k)*H + q);
    }
    __syncthreads();
    #pragma unroll 4
    for (int k = 0; k < 32; ++k) {
      float4 a4 = *(const float4*)&At[k*68 + 4*tgn];
      float4 b0 = *(const float4*)&Bl[k*128 + 8*tgw];
      float4 b1 = *(const float4*)&Bl[k*128 + 8*tgw + 4];
      float av[4] = {a4.x, a4.y, a4.z, a4.w};
      float bvv[8] = {b0.x, b0.y, b0.z, b0.w, b1.x, b1.y, b1.z, b1.w};
      #pragma unroll
      for (int r = 0; r < 4; ++r)
        #pragma unroll
        for (int c = 0; c < 8; ++c)
          acc[r][c] += av[r] * bvv[c];
    }
    __syncthreads();
  }
  #pragma unroll
  for (int r = 0; r < 4; ++r) {
    size_t row = (size_t)ks*N_PTS + n0 + 4*tgn + r;
    *(float4*)(out_part + row*H + 8*tgw)     = make_float4(acc[r][0], acc[r][1], acc[r][2], acc[r][3]);
    *(float4*)(out_part + row*H + 8*tgw + 4) = make_float4(acc[r][4], acc[r][5], acc[r][6], acc[r][7]);
  }
}

// ---------------------------------------------------------------------------
// K5: reduce split-K partials, post-MLP (W_post + b_post) and silu -> d_out
// ---------------------------------------------------------------------------
__global__ __launch_bounds__(128) void k_post(const float* __restrict__ out_part,
    const float* __restrict__ W_post, const float* __restrict__ b_post,
    float* __restrict__ out) {
  __shared__ float op[8 * H];
  int t = threadIdx.x;
  int n0 = blockIdx.x * 8;
  #pragma unroll
  for (int n = 0; n < 8; ++n) {
    float v = 0.0f;
    #pragma unroll
    for (int s = 0; s < 8; ++s)
      v += out_part[((size_t)s*N_PTS + n0 + n)*H + t];
    op[n*H + t] = v;
  }
  __syncthreads();
  float acc[8] = {};
  #pragma unroll 4
  for (int u = 0; u < H; ++u) {
    float wp = W_post[u*H + t];
    #pragma unroll
    for (int n = 0; n < 8; ++n)
      acc[n] += op[n*H + u] * wp;
  }
  float bp = b_post[t];
  #pragma unroll
  for (int n = 0; n < 8; ++n)
    out[(size_t)(n0 + n)*H + t] = silu_f(acc[n] + bp);
}

// ---------------------------------------------------------------------------
extern "C" void kernel_launch(void* const* d_in, const int* in_sizes, int n_in,
                              void* d_out, int out_size, void* d_ws, size_t ws_size,
                              hipStream_t stream) {
  const float* h      = (const float*)d_in[0];
  const float* gc     = (const float*)d_in[1];
  const float* cc     = (const float*)d_in[2];
  const float* gw     = (const float*)d_in[3];
  const float* W_pre  = (const float*)d_in[4];
  const float* b_pre  = (const float*)d_in[5];
  const float* W_down = (const float*)d_in[6];
  const float* W_up   = (const float*)d_in[7];
  const float* W_post = (const float*)d_in[8];
  const float* b_post = (const float*)d_in[9];

  float* ws       = (float*)d_ws;
  float* SH       = ws;                     // 2048*128*12      = 3,145,728 f
  float* hdg      = SH + 3145728;           // 3*2048*128       =   786,432 f
  float* c_part   = hdg + 786432;           // 32*128*9*128     = 4,718,592 f
  float* CU       = c_part + 4718592;       // 128*12*128       =   196,608 f
  // out_part aliases c_part: c_part is dead after k_cu, and out_part
  // (8*2048*128 = 2,097,152 f) fits inside it.
  float* out_part = c_part;
  float* out      = (float*)d_out;

  k_sh  <<<1024,          256, 0, stream>>>(gc, cc, SH);
  k_pre <<<256,           128, 0, stream>>>(h, W_pre, b_pre, W_down, gw, hdg);
  k_down<<<dim3(32,32),   128, 0, stream>>>(SH, hdg, c_part);
  k_cu  <<<dim3(128,3),   128, 0, stream>>>(c_part, W_up, CU);
  k_up  <<<dim3(32,8),    256, 0, stream>>>(SH, CU, out_part);
  k_post<<<256,           128, 0, stream>>>(out_part, W_post, b_post, out);
}

// Round 3
// 161.815 us; speedup vs baseline: 1.6165x; 1.6165x over previous
//
#include <hip/hip_runtime.h>
#include <math.h>

#define N_PTS 2048
#define M_PTS 128
#define INNF  256
#define H     128

#define MIN_STDC 0.30235680f   /* 0.32*1.88973/2 */
#define MAX_STDC 2.19208680f   /* 2.32*1.88973/2 */
#define PI_F     3.14159265358979f
#define LOG2E_F  1.44269504089f

static __device__ __forceinline__ float silu_f(float x) {
  return x / (1.0f + __expf(-x));
}

// ---------------------------------------------------------------------------
// K0: spherical harmonics + d^2 for all (n,m) pairs (consumed by k_up only;
// k_down recomputes its tile in LDS).
// SH layout [n][m][12]: {1, x, y, z, s3xz, s3xy, yy-0.5(xx+zz), s3yz,
//                        0.5*s3*(zz-xx), d2, 0, 0}
// ---------------------------------------------------------------------------
__global__ __launch_bounds__(256) void k_sh(const float* __restrict__ gc,
                                            const float* __restrict__ cc,
                                            float* __restrict__ SH) {
  int p = blockIdx.x * 256 + threadIdx.x;     // 0 .. N*M-1
  int n = p >> 7, m = p & 127;
  float gx = gc[3*n], gy = gc[3*n+1], gz = gc[3*n+2];
  float cx = cc[3*m], cy = cc[3*m+1], cz = cc[3*m+2];
  float dx = gx - cx, dy = gy - cy, dz = gz - cz;
  float d2 = dx*dx + dy*dy + dz*dz + 3e-20f;
  float inv = rsqrtf(d2);
  float x = dx*inv, y = dy*inv, z = dz*inv;
  const float s3 = 1.73205080757f;
  float4 q0 = make_float4(1.0f, x, y, z);
  float4 q1 = make_float4(s3*x*z, s3*x*y, y*y - 0.5f*(x*x + z*z), s3*y*z);
  float4 q2 = make_float4(0.5f*s3*(z*z - x*x), d2, 0.0f, 0.0f);
  float4* dst = (float4*)(SH + (size_t)p * 12);
  dst[0] = q0; dst[1] = q1; dst[2] = q2;
}

// ---------------------------------------------------------------------------
// K1: hpre = silu(h @ W_pre + b_pre), then
//     hdg4[n][w][l] = (hpre @ W_down[l])[n,w] * gw[n] * coef(w) / sqrt(2l+1)
// 4 n-rows per block, 256 threads (w = t&127, nh = t>>7 covers 2 n each).
// LDS row-major (broadcast reads, no conflicts); weights per-lane coalesced.
// ---------------------------------------------------------------------------
__global__ __launch_bounds__(256) void k_pre(const float* __restrict__ h,
    const float* __restrict__ W_pre, const float* __restrict__ b_pre,
    const float* __restrict__ W_down, const float* __restrict__ gw,
    float* __restrict__ hdg4) {
  __shared__ float h_lds[4 * INNF];    // [n_loc][u]
  __shared__ float hp_lds[4 * H];      // [n_loc][u]
  int t = threadIdx.x;
  int n0 = blockIdx.x * 4;
  int w  = t & 127;
  int nh = t >> 7;

  // stage h rows (coalesced float4, conflict-free b128 LDS writes)
  {
    int row = t >> 6, col = (t & 63) << 2;
    float4 v = *(const float4*)(h + (size_t)(n0 + row) * INNF + col);
    *(float4*)&h_lds[row * INNF + col] = v;
  }
  __syncthreads();

  // stage 1: hpre rows n_loc = nh*2 + {0,1}
  float acc[2] = {0.0f, 0.0f};
  for (int u = 0; u < INNF; u += 4) {
    float4 a0 = *(const float4*)&h_lds[(nh*2 + 0) * INNF + u];
    float4 a1 = *(const float4*)&h_lds[(nh*2 + 1) * INNF + u];
    float w0 = W_pre[(u+0)*H + w];
    float w1 = W_pre[(u+1)*H + w];
    float w2 = W_pre[(u+2)*H + w];
    float w3 = W_pre[(u+3)*H + w];
    acc[0] += a0.x*w0 + a0.y*w1 + a0.z*w2 + a0.w*w3;
    acc[1] += a1.x*w0 + a1.y*w1 + a1.z*w2 + a1.w*w3;
  }
  float bb = b_pre[w];
  hp_lds[(nh*2 + 0)*H + w] = silu_f(acc[0] + bb);
  hp_lds[(nh*2 + 1)*H + w] = silu_f(acc[1] + bb);
  __syncthreads();

  // per-w folded radial coefficient
  const float stp = (MAX_STDC - MIN_STDC) / 127.0f;
  float s = MIN_STDC + (float)w * stp;
  float temps = 2.0f * s * s;
  float coef = (2.0f/3.0f) / (temps * powf(PI_F * temps, 1.5f));
  float gwv[2] = {gw[n0 + nh*2], gw[n0 + nh*2 + 1]};
  const float invn[3] = {1.0f, 0.57735026919f, 0.44721359550f};

  // stage 2: 3 l's x 2 n's
  float a2[3][2] = {};
  for (int u = 0; u < H; u += 4) {
    float4 p0 = *(const float4*)&hp_lds[(nh*2 + 0)*H + u];
    float4 p1 = *(const float4*)&hp_lds[(nh*2 + 1)*H + u];
    #pragma unroll
    for (int l = 0; l < 3; ++l) {
      float w0 = W_down[((size_t)l*H + u + 0)*H + w];
      float w1 = W_down[((size_t)l*H + u + 1)*H + w];
      float w2 = W_down[((size_t)l*H + u + 2)*H + w];
      float w3 = W_down[((size_t)l*H + u + 3)*H + w];
      a2[l][0] += p0.x*w0 + p0.y*w1 + p0.z*w2 + p0.w*w3;
      a2[l][1] += p1.x*w0 + p1.y*w1 + p1.z*w2 + p1.w*w3;
    }
  }
  #pragma unroll
  for (int r = 0; r < 2; ++r) {
    float sc = gwv[r] * coef;
    size_t base = ((size_t)(n0 + nh*2 + r) * H + w) * 4;
    hdg4[base + 0] = a2[0][0+0]*0.0f + a2[0][r]*sc;          // l=0
    hdg4[base + 1] = a2[1][r]*sc*invn[1];                    // l=1
    hdg4[base + 2] = a2[2][r]*sc*invn[2];                    // l=2
    hdg4[base + 3] = 0.0f;
  }
}

// ---------------------------------------------------------------------------
// K2: pair loop ("down"). SH tile computed in LDS; lane = w; 256 threads
// (nh = t>>7 splits the 64-n chunk), m-tile 4, grid (32 mg, 32 s) -> 16 w/CU.
// ---------------------------------------------------------------------------
__global__ __launch_bounds__(256) void k_down(const float* __restrict__ gc,
    const float* __restrict__ cc, const float* __restrict__ hdg4,
    float* __restrict__ c_part) {
  __shared__ float lds[4608];          // SH tile 64n*4m*12 = 3072f; reused 4608f for reduce
  int t = threadIdx.x;
  int m0 = blockIdx.x * 4;
  int ss = blockIdx.y;                 // 0..31
  int n0 = ss * 64;
  int w  = t & 127;
  int nh = t >> 7;

  // phase 0: each thread computes one (n_loc, m_loc) pair's SH into LDS
  {
    int n_loc = t >> 2, m_loc = t & 3;
    int n = n0 + n_loc, m = m0 + m_loc;
    float dx = gc[3*n]   - cc[3*m];
    float dy = gc[3*n+1] - cc[3*m+1];
    float dz = gc[3*n+2] - cc[3*m+2];
    float d2 = dx*dx + dy*dy + dz*dz + 3e-20f;
    float inv = rsqrtf(d2);
    float x = dx*inv, y = dy*inv, z = dz*inv;
    const float s3 = 1.73205080757f;
    float* dst = &lds[(size_t)t * 12];
    dst[0] = 1.0f; dst[1] = x; dst[2] = y; dst[3] = z;
    dst[4] = s3*x*z; dst[5] = s3*x*y; dst[6] = y*y - 0.5f*(x*x + z*z);
    dst[7] = s3*y*z; dst[8] = 0.5f*s3*(z*z - x*x);
    dst[9] = d2; dst[10] = 0.0f; dst[11] = 0.0f;
  }
  __syncthreads();

  const float stp = (MAX_STDC - MIN_STDC) / 127.0f;
  float sw = MIN_STDC + (float)w * stp;
  float nl2t = LOG2E_F / (2.0f * sw * sw);

  float acc[4][9] = {};
  for (int j = 0; j < 32; j += 2) {
    int nA = nh*32 + j, nB = nA + 1;
    float4 hA = *(const float4*)(hdg4 + ((size_t)(n0 + nA)*H + w)*4);
    float4 hB = *(const float4*)(hdg4 + ((size_t)(n0 + nB)*H + w)*4);
    #pragma unroll
    for (int half = 0; half < 2; ++half) {
      int nl = half ? nB : nA;
      float4 hv = half ? hB : hA;
      const float* shb = &lds[(size_t)nl * 48];
      #pragma unroll
      for (int mm = 0; mm < 4; ++mm) {
        float4 q0 = *(const float4*)(shb + mm*12);
        float4 q1 = *(const float4*)(shb + mm*12 + 4);
        float4 q2 = *(const float4*)(shb + mm*12 + 8);
        float e  = exp2f(-q2.y * nl2t);
        float rp = e * q2.y;
        float t0 = hv.x*rp, t1 = hv.y*rp, t2 = hv.z*rp;
        acc[mm][0] += t0;
        acc[mm][1] += t1*q0.y; acc[mm][2] += t1*q0.z; acc[mm][3] += t1*q0.w;
        acc[mm][4] += t2*q1.x; acc[mm][5] += t2*q1.y;
        acc[mm][6] += t2*q1.z; acc[mm][7] += t2*q1.w;
        acc[mm][8] += t2*q2.x;
      }
    }
  }

  // cross-nh reduce via LDS, then store
  __syncthreads();
  if (nh == 1) {
    #pragma unroll
    for (int mm = 0; mm < 4; ++mm)
      #pragma unroll
      for (int li = 0; li < 9; ++li)
        lds[(mm*9 + li)*128 + w] = acc[mm][li];
  }
  __syncthreads();
  if (nh == 0) {
    #pragma unroll
    for (int mm = 0; mm < 4; ++mm)
      #pragma unroll
      for (int li = 0; li < 9; ++li) {
        float v = acc[mm][li] + lds[(mm*9 + li)*128 + w];
        c_part[(((size_t)ss*M_PTS + m0 + mm)*9 + li)*H + w] = v;
      }
  }
}

// ---------------------------------------------------------------------------
// K3: per-m: reduce 32 s-partials into LDS, then CU[m][li][w] via W_up.
// 256 threads: uh = t>>7 splits the u-loop; LDS cross-reduce at the end.
// ---------------------------------------------------------------------------
__global__ __launch_bounds__(256) void k_cu(const float* __restrict__ c_part,
    const float* __restrict__ W_up, float* __restrict__ CU) {
  __shared__ float c_lds[H * 12];      // [u][li] (li 9..11 unused)
  __shared__ float red[9 * H];
  int t = threadIdx.x, m = blockIdx.x;
  int w = t & 127, uh = t >> 7;

  for (int idx = t; idx < 9 * H; idx += 256) {
    int li = idx >> 7, u = idx & 127;
    float v = 0.0f;
    #pragma unroll 8
    for (int s = 0; s < 32; ++s)
      v += c_part[(((size_t)s*M_PTS + m)*9 + li)*H + u];
    c_lds[u*12 + li] = v;
  }
  __syncthreads();

  float acc[9] = {};
  for (int u = uh*64; u < uh*64 + 64; ++u) {
    float4 q0 = *(const float4*)&c_lds[u*12];
    float4 q1 = *(const float4*)&c_lds[u*12 + 4];
    float  q8 = c_lds[u*12 + 8];
    float w0 = W_up[((size_t)0*H + u)*H + w];
    float w1 = W_up[((size_t)1*H + u)*H + w];
    float w2 = W_up[((size_t)2*H + u)*H + w];
    acc[0] += q0.x*w0;
    acc[1] += q0.y*w1; acc[2] += q0.z*w1; acc[3] += q0.w*w1;
    acc[4] += q1.x*w2; acc[5] += q1.y*w2; acc[6] += q1.z*w2;
    acc[7] += q1.w*w2; acc[8] += q8*w2;
  }
  __syncthreads();
  if (uh == 1) {
    #pragma unroll
    for (int li = 0; li < 9; ++li) red[li*128 + w] = acc[li];
  }
  __syncthreads();
  if (uh == 0) {
    const float invn[3] = {1.0f, 0.57735026919f, 0.44721359550f};
    #pragma unroll
    for (int li = 0; li < 9; ++li) {
      int l = (li == 0) ? 0 : (li < 4 ? 1 : 2);
      CU[((size_t)m*12 + li)*H + w] = (acc[li] + red[li*128 + w]) * invn[l];
    }
    #pragma unroll
    for (int li = 9; li < 12; ++li)
      CU[((size_t)m*12 + li)*H + w] = 0.0f;
  }
}

// ---------------------------------------------------------------------------
// K4: up GEMM  out_pre[2048 x 128] = SH[2048 x 1536] @ CU[1536 x 128],
// split-K 16 chunks of 96. Block tile 64n x 128w, thread tile 4n x 8w.
// ---------------------------------------------------------------------------
__global__ __launch_bounds__(256) void k_up(const float* __restrict__ SH,
    const float* __restrict__ CU, float* __restrict__ out_part) {
  __shared__ float At[32 * 65];    // [k][n] pad 65: conflict-light staging
  __shared__ float Bl[32 * 128];   // [k][w]
  int t = threadIdx.x;
  int n0 = blockIdx.x * 64;
  int ks = blockIdx.y;
  int tgn = t >> 4, tgw = t & 15;
  float acc[4][8] = {};
  for (int ch = 0; ch < 3; ++ch) {
    int kc = ks*96 + ch*32;
    #pragma unroll
    for (int i = 0; i < 2; ++i) {           // stage A (transposed)
      int idx = t + i*256;
      int n = idx >> 3, q = (idx & 7) << 2;
      float4 v = *(const float4*)(SH + (size_t)(n0 + n)*1536 + kc + q);
      At[(q+0)*65 + n] = v.x; At[(q+1)*65 + n] = v.y;
      At[(q+2)*65 + n] = v.z; At[(q+3)*65 + n] = v.w;
    }
    #pragma unroll
    for (int i = 0; i < 4; ++i) {           // stage B
      int idx = t + i*256;
      int k = idx >> 5, q = (idx & 31) << 2;
      *(float4*)&Bl[k*128 + q] = *(const float4*)(CU + (size_t)(kc + k)*H + q);
    }
    __syncthreads();
    #pragma unroll 4
    for (int k = 0; k < 32; ++k) {
      float4 a4 = *(const float4*)&At[k*65 + 4*tgn];
      float4 b0 = *(const float4*)&Bl[k*128 + 8*tgw];
      float4 b1 = *(const float4*)&Bl[k*128 + 8*tgw + 4];
      float av[4] = {a4.x, a4.y, a4.z, a4.w};
      float bvv[8] = {b0.x, b0.y, b0.z, b0.w, b1.x, b1.y, b1.z, b1.w};
      #pragma unroll
      for (int r = 0; r < 4; ++r)
        #pragma unroll
        for (int c = 0; c < 8; ++c)
          acc[r][c] += av[r] * bvv[c];
    }
    __syncthreads();
  }
  #pragma unroll
  for (int r = 0; r < 4; ++r) {
    size_t row = (size_t)ks*N_PTS + n0 + 4*tgn + r;
    *(float4*)(out_part + row*H + 8*tgw)     = make_float4(acc[r][0], acc[r][1], acc[r][2], acc[r][3]);
    *(float4*)(out_part + row*H + 8*tgw + 4) = make_float4(acc[r][4], acc[r][5], acc[r][6], acc[r][7]);
  }
}

// ---------------------------------------------------------------------------
// K5: reduce 16 split-K partials, post-MLP + silu -> d_out.
// 4 n-rows per block, 256 threads, 512 blocks.
// ---------------------------------------------------------------------------
__global__ __launch_bounds__(256) void k_post(const float* __restrict__ out_part,
    const float* __restrict__ W_post, const float* __restrict__ b_post,
    float* __restrict__ out) {
  __shared__ float op[4 * H];
  int t = threadIdx.x;
  int n0 = blockIdx.x * 4;
  int w = t & 127, nh = t >> 7;

  #pragma unroll
  for (int i = 0; i < 2; ++i) {
    int idx = t + i*256;                 // 0..511
    int nl = idx >> 7, ww = idx & 127;
    float v = 0.0f;
    #pragma unroll
    for (int s = 0; s < 16; ++s)
      v += out_part[((size_t)s*N_PTS + n0 + nl)*H + ww];
    op[nl*H + ww] = v;
  }
  __syncthreads();

  float acc[2] = {0.0f, 0.0f};
  for (int u = 0; u < H; u += 4) {
    float4 p0 = *(const float4*)&op[(nh*2 + 0)*H + u];
    float4 p1 = *(const float4*)&op[(nh*2 + 1)*H + u];
    float w0 = W_post[(u+0)*H + w];
    float w1 = W_post[(u+1)*H + w];
    float w2 = W_post[(u+2)*H + w];
    float w3 = W_post[(u+3)*H + w];
    acc[0] += p0.x*w0 + p0.y*w1 + p0.z*w2 + p0.w*w3;
    acc[1] += p1.x*w0 + p1.y*w1 + p1.z*w2 + p1.w*w3;
  }
  float bp = b_post[w];
  out[(size_t)(n0 + nh*2 + 0)*H + w] = silu_f(acc[0] + bp);
  out[(size_t)(n0 + nh*2 + 1)*H + w] = silu_f(acc[1] + bp);
}

// ---------------------------------------------------------------------------
extern "C" void kernel_launch(void* const* d_in, const int* in_sizes, int n_in,
                              void* d_out, int out_size, void* d_ws, size_t ws_size,
                              hipStream_t stream) {
  const float* h      = (const float*)d_in[0];
  const float* gc     = (const float*)d_in[1];
  const float* cc     = (const float*)d_in[2];
  const float* gw     = (const float*)d_in[3];
  const float* W_pre  = (const float*)d_in[4];
  const float* b_pre  = (const float*)d_in[5];
  const float* W_down = (const float*)d_in[6];
  const float* W_up   = (const float*)d_in[7];
  const float* W_post = (const float*)d_in[8];
  const float* b_post = (const float*)d_in[9];

  float* ws       = (float*)d_ws;
  float* SH       = ws;                     // 2048*128*12      = 3,145,728 f
  float* hdg4     = SH + 3145728;           // 2048*128*4       = 1,048,576 f
  float* c_part   = hdg4 + 1048576;         // 32*128*9*128     = 4,718,592 f
  float* CU       = c_part + 4718592;       // 128*12*128       =   196,608 f
  // out_part (16*2048*128 = 4,194,304 f) aliases c_part (dead after k_cu)
  float* out_part = c_part;
  float* out      = (float*)d_out;

  k_sh  <<<1024,          256, 0, stream>>>(gc, cc, SH);
  k_pre <<<512,           256, 0, stream>>>(h, W_pre, b_pre, W_down, gw, hdg4);
  k_down<<<dim3(32,32),   256, 0, stream>>>(gc, cc, hdg4, c_part);
  k_cu  <<<128,           256, 0, stream>>>(c_part, W_up, CU);
  k_up  <<<dim3(32,16),   256, 0, stream>>>(SH, CU, out_part);
  k_post<<<512,           256, 0, stream>>>(out_part, W_post, b_post, out);
}